// Round 11
// baseline (4789.799 us; speedup 1.0000x reference)
//
#include <hip/hip_runtime.h>
#include <hip/hip_bf16.h>

#define CB 256      // batch
#define CN 256      // nodes
#define CK 3        // children per node
#define CE 256      // embedding dim
#define CH 256      // hidden dim
#define CG_ 1536    // gates = 6*CH
#define KTOT 1024   // E + K*H
#define APAD 8
#define ASTR (KTOT + APAD)   // LDS A row stride (shorts) = 1032 (2064 B)

typedef __attribute__((ext_vector_type(8))) short short8v;          // 8 bf16
typedef __attribute__((ext_vector_type(4))) float float4v;          // MFMA C/D
typedef __attribute__((ext_vector_type(4))) unsigned int uint4v;    // 16B copy
typedef __attribute__((ext_vector_type(4))) unsigned short ushort4v;// 8B store

__device__ __forceinline__ unsigned short f2bfu(float v) {
    __hip_bfloat16 h = __float2bfloat16(v);
    return __builtin_bit_cast(unsigned short, h);
}
__device__ __forceinline__ float bfu2f(unsigned short u) {
    __hip_bfloat16 h = __builtin_bit_cast(__hip_bfloat16, u);
    return __bfloat162float(h);
}

// ---------------------------------------------------------------------------
// Prep (verified r8-r10): split virtual W = [Wx_w ; Uh_w] (1024 x 1536) into
// K-major bf16 hi/lo planes [g][k].
// ---------------------------------------------------------------------------
__global__ __launch_bounds__(256) void prep_w(
    const float* __restrict__ Wx_w, const float* __restrict__ Uh_w,
    unsigned short* __restrict__ Whi, unsigned short* __restrict__ Wlo)
{
    const int g = blockIdx.x;
    for (int k = threadIdx.x; k < KTOT; k += 256) {
        float w = (k < CE) ? Wx_w[(size_t)k * CG_ + g]
                           : Uh_w[(size_t)(k - CE) * CG_ + g];
        unsigned short hi = f2bfu(w);
        Whi[(size_t)g * KTOT + k] = hi;
        Wlo[(size_t)g * KTOT + k] = f2bfu(w - bfu2f(hi));
    }
}

// ---------------------------------------------------------------------------
// One tree step per launch. 256 blocks x 768 threads (12 waves).
// r11 changes vs r10 (structure/math identical, verified absmax 1.22e-4):
//  - B-panel prefetch (ci=0..2) issued BEFORE staging: B-loads depend on
//    nothing local, so they stream from L2 while staging runs.
//  - Non-temporal loads/stores on all streaming traffic (h gathers, emb
//    rows, c reads, h/c writes) so the W panels stay L2-resident.
//  - part[] padded [16][17] to kill the 4-way bank conflict on writes.
// ---------------------------------------------------------------------------
__global__ __launch_bounds__(768) void tree_step_mfma(
    const int* __restrict__ node_ids,          // [B][N]
    const int* __restrict__ children,          // [B][N][K]
    const float* __restrict__ emb,             // [V][E]
    const unsigned short* __restrict__ Whi,    // [1536][1024]
    const unsigned short* __restrict__ Wlo,    // [1536][1024]
    const float* __restrict__ Wx_b,            // [G]
    const float* __restrict__ Uh_b,            // [K][G]
    unsigned short* __restrict__ h_hi,         // [N][B][H] bf16 hi plane
    unsigned short* __restrict__ h_lo,         // [N][B][H] bf16 lo plane
    float* __restrict__ c_s,                   // [N][B][H] f32
    float* __restrict__ out,                   // [B][H] f32
    const int t)
{
    const int tid = threadIdx.x;

    const int xcd  = blockIdx.x & 7;
    const int bidx = blockIdx.x >> 3;
    const int hi   = xcd * 2 + (bidx & 1);
    const int bi   = bidx >> 1;
    const int b0   = bi * 16;
    const int hh0  = hi * 16;

    __shared__ unsigned short Ahi[16][ASTR];   // 33,024 B
    __shared__ unsigned short Alo[16][ASTR];   // 33,024 B
    __shared__ float part[4][6][16][17];       // 26,112 B (pad 17: no 4-way conflict)
    __shared__ int   nid[16];
    __shared__ float msk[16][3];
    __shared__ int   cix[16][3];

    const int wv    = tid >> 6;                // 0..11
    const int l     = tid & 63;
    const int np    = wv % 3;                  // N-pair
    const int kq    = wv / 3;                  // K-quarter
    const int lan15 = l & 15;
    const int k8    = (l >> 4) * 8;

    // B column byte bases per q-tile pair (independent of LDS/staging)
    size_t bbase[2];
    #pragma unroll
    for (int t2 = 0; t2 < 2; ++t2)
        bbase[t2] = (size_t)((np * 2 + t2) * CH + hh0 + lan15) * KTOT + k8;

    // --- B prefetch for ci = 0..2: in flight during mask setup + staging ---
    short8v pbh[3][2], pbl[3][2];
    #pragma unroll
    for (int p = 0; p < 3; ++p) {
        const int kbg = (kq * 8 + p) * 32;
        #pragma unroll
        for (int t2 = 0; t2 < 2; ++t2) {
            pbh[p][t2] = *(const short8v*)(Whi + bbase[t2] + kbg);
            pbl[p][t2] = *(const short8v*)(Wlo + bbase[t2] + kbg);
        }
    }

    if (tid < 16) nid[tid] = node_ids[(size_t)(b0 + tid) * CN + t];
    if (tid < 48) {
        int lb = tid / 3, k = tid - lb * 3;
        int raw = children[((size_t)(b0 + lb) * CN + t) * CK + k];
        int v = raw < t;
        msk[lb][k] = v ? 1.0f : 0.0f;
        cix[lb][k] = v ? raw : 0;
    }
    __syncthreads();

    // stage x: 16 rows x 64 float4 chunks; split hi/lo in-register (nt loads)
    for (int idx = tid; idx < 1024; idx += 768) {
        int lb = idx >> 6, c4 = idx & 63;
        float4v v = __builtin_nontemporal_load(
            (const float4v*)(emb + (size_t)nid[lb] * CE + c4 * 4));
        ushort4v h4, l4;
        #pragma unroll
        for (int j = 0; j < 4; ++j) {
            unsigned short hb = f2bfu(v[j]);
            h4[j] = hb;
            l4[j] = f2bfu(v[j] - bfu2f(hb));
        }
        *(ushort4v*)&Ahi[lb][c4 * 4] = h4;
        *(ushort4v*)&Alo[lb][c4 * 4] = l4;
    }
    // stage h: 48 rows x (32 hi + 32 lo) 16B chunks (nt loads)
    for (int idx = tid; idx < 3072; idx += 768) {
        int r  = idx >> 6;                 // 0..47
        int c  = idx & 63;
        int pl = c >> 5;                   // 0=hi, 1=lo
        int ch = c & 31;                   // 16B chunk in row
        int lb = r / 3, k = r - lb * 3;
        uint4v val = (uint4v){0u, 0u, 0u, 0u};
        if (msk[lb][k] != 0.0f) {
            const unsigned short* src = (pl ? h_lo : h_hi)
                + ((size_t)cix[lb][k] * CB + (b0 + lb)) * CH + ch * 8;
            val = __builtin_nontemporal_load((const uint4v*)src);
        }
        unsigned short* dst = (pl ? &Alo[lb][CE + k * CH + ch * 8]
                                  : &Ahi[lb][CE + k * CH + ch * 8]);
        *(uint4v*)dst = val;
    }
    __syncthreads();

    // MFMA bf16x3: 8 k-iters per wave, 2 q-tiles, 3 chains
    {
        float4v acc[2][3];
        #pragma unroll
        for (int a = 0; a < 2; ++a)
            #pragma unroll
            for (int b = 0; b < 3; ++b)
                acc[a][b] = (float4v){0.f, 0.f, 0.f, 0.f};

        #pragma unroll
        for (int ci = 0; ci < 8; ++ci) {
            const int kb = (kq * 8 + ci) * 32 + k8;
            short8v ahi = *(const short8v*)&Ahi[lan15][kb];
            short8v alo = *(const short8v*)&Alo[lan15][kb];
            short8v bh[2], bl[2];
            if (ci < 3) {
                #pragma unroll
                for (int t2 = 0; t2 < 2; ++t2) { bh[t2] = pbh[ci][t2]; bl[t2] = pbl[ci][t2]; }
            } else {
                const int kbg = (kq * 8 + ci) * 32;
                #pragma unroll
                for (int t2 = 0; t2 < 2; ++t2) {
                    bh[t2] = *(const short8v*)(Whi + bbase[t2] + kbg);
                    bl[t2] = *(const short8v*)(Wlo + bbase[t2] + kbg);
                }
            }
            #pragma unroll
            for (int t2 = 0; t2 < 2; ++t2) {
                acc[t2][0] = __builtin_amdgcn_mfma_f32_16x16x32_bf16(ahi, bh[t2], acc[t2][0], 0, 0, 0);
                acc[t2][1] = __builtin_amdgcn_mfma_f32_16x16x32_bf16(ahi, bl[t2], acc[t2][1], 0, 0, 0);
                acc[t2][2] = __builtin_amdgcn_mfma_f32_16x16x32_bf16(alo, bh[t2], acc[t2][2], 0, 0, 0);
            }
        }
        #pragma unroll
        for (int t2 = 0; t2 < 2; ++t2)
            #pragma unroll
            for (int r = 0; r < 4; ++r)
                part[kq][np * 2 + t2][(l >> 4) * 4 + r][lan15] =
                    acc[t2][0][r] + acc[t2][1][r] + acc[t2][2][r];
    }
    __syncthreads();

    // cell phase (r7-verified math; h written pre-split, nt stores)
    if (tid < 256) {
        const int bb = tid >> 4, j2 = tid & 15;
        const int b = b0 + bb, hh = hh0 + j2;
        const float m0 = msk[bb][0], m1 = msk[bb][1], m2 = msk[bb][2];
        float g[6];
        #pragma unroll
        for (int q = 0; q < 6; ++q) {
            int gc = q * CH + hh;
            g[q] = part[0][q][bb][j2] + part[1][q][bb][j2]
                 + part[2][q][bb][j2] + part[3][q][bb][j2]
                 + Wx_b[gc] + m0 * Uh_b[gc] + m1 * Uh_b[CG_ + gc]
                            + m2 * Uh_b[2 * CG_ + gc];
        }
        float ig = 1.0f / (1.0f + expf(-g[0]));
        float og = 1.0f / (1.0f + expf(-g[1]));
        float ug = tanhf(g[2]);
        float c = ig * ug;
        if (m0 != 0.0f) c += (1.0f / (1.0f + expf(-g[3]))) *
            __builtin_nontemporal_load(&c_s[((size_t)cix[bb][0] * CB + b) * CH + hh]);
        if (m1 != 0.0f) c += (1.0f / (1.0f + expf(-g[4]))) *
            __builtin_nontemporal_load(&c_s[((size_t)cix[bb][1] * CB + b) * CH + hh]);
        if (m2 != 0.0f) c += (1.0f / (1.0f + expf(-g[5]))) *
            __builtin_nontemporal_load(&c_s[((size_t)cix[bb][2] * CB + b) * CH + hh]);
        float h = og * tanhf(c);
        const size_t hx = ((size_t)t * CB + b) * CH + hh;
        unsigned short hb = f2bfu(h);
        __builtin_nontemporal_store(hb, &h_hi[hx]);
        __builtin_nontemporal_store(f2bfu(h - bfu2f(hb)), &h_lo[hx]);
        __builtin_nontemporal_store(c, &c_s[hx]);
        if (t == CN - 1) out[(size_t)b * CH + hh] = h;
    }
}

// ---------------------------------------------------------------------------
// Fallback (r7-verified fp32 per-step kernel), used only if ws too small.
// ---------------------------------------------------------------------------
__global__ __launch_bounds__(512) void tree_step(
    const int* __restrict__ node_ids, const int* __restrict__ children,
    const float* __restrict__ emb, const float* __restrict__ Wx_w,
    const float* __restrict__ Wx_b, const float* __restrict__ Uh_w,
    const float* __restrict__ Uh_b, float* __restrict__ h_s,
    float* __restrict__ c_s, float* __restrict__ out, const int t)
{
    const int tid = threadIdx.x;
    const int xcd  = blockIdx.x & 7;
    const int bidx = blockIdx.x >> 3;
    const int hi   = xcd * 2 + (bidx & 1);
    const int bi   = bidx >> 1;
    const int b0   = bi * 16;
    const int hh0  = hi * 16;
    const int tt   = tid >> 6;
    const int lane = tid & 63;
    const int bq   = lane >> 4;
    const int jj   = lane & 15;

    __shared__ float xh[16][1025];
    __shared__ float gred[8][16][6][16];
    __shared__ int   nid[16];
    __shared__ float msk[16][3];
    __shared__ int   cix[16][3];

    if (tid < 16) nid[tid] = node_ids[(size_t)(b0 + tid) * CN + t];
    if (tid < 48) {
        int lb = tid / 3, k = tid - lb * 3;
        int raw = children[((size_t)(b0 + lb) * CN + t) * CK + k];
        int v = raw < t;
        msk[lb][k] = v ? 1.0f : 0.0f;
        cix[lb][k] = v ? raw : 0;
    }
    __syncthreads();
    for (int i = 0; i < 32; ++i) {
        int id2 = tid + (i << 9);
        int lb  = id2 >> 10;
        int col = id2 & 1023;
        float v;
        if (col < CE) v = emb[(size_t)nid[lb] * CE + col];
        else {
            int k  = (col - CE) >> 8;
            int hc = col & 255;
            v = 0.0f;
            if (msk[lb][k] != 0.0f)
                v = h_s[((size_t)cix[lb][k] * CB + (b0 + lb)) * CH + hc];
        }
        xh[lb][col] = v;
    }
    __syncthreads();
    float acc[4][6] = {};
    {
        const float* w0p = (tt < 2)
            ? (Wx_w + (size_t)(tt * 128) * CG_ + (hh0 + jj))
            : (Uh_w + (size_t)(tt * 128 - 256) * CG_ + (hh0 + jj));
        const int colbase = tt * 128;
        #pragma unroll 4
        for (int kl = 0; kl < 128; ++kl) {
            const float* wr = w0p + (size_t)kl * CG_;
            float w0 = wr[0], w1 = wr[256], w2 = wr[512];
            float w3 = wr[768], w4 = wr[1024], w5 = wr[1280];
            int col = colbase + kl;
            #pragma unroll
            for (int r = 0; r < 4; ++r) {
                float hv = xh[bq + 4 * r][col];
                acc[r][0] += hv * w0; acc[r][1] += hv * w1; acc[r][2] += hv * w2;
                acc[r][3] += hv * w3; acc[r][4] += hv * w4; acc[r][5] += hv * w5;
            }
        }
    }
    #pragma unroll
    for (int r = 0; r < 4; ++r)
        #pragma unroll
        for (int q = 0; q < 6; ++q)
            gred[tt][bq + 4 * r][q][jj] = acc[r][q];
    __syncthreads();
    if (tid < 256) {
        const int bb = tid >> 4, j2 = tid & 15;
        const int b = b0 + bb, hh = hh0 + j2;
        float g[6];
        #pragma unroll
        for (int q = 0; q < 6; ++q) {
            float s = 0.0f;
            #pragma unroll
            for (int k = 0; k < 8; ++k) s += gred[k][bb][q][j2];
            g[q] = s;
        }
        const float m0 = msk[bb][0], m1 = msk[bb][1], m2 = msk[bb][2];
        #pragma unroll
        for (int q = 0; q < 6; ++q) {
            int gc = q * CH + hh;
            g[q] += Wx_b[gc] + m0 * Uh_b[gc] + m1 * Uh_b[CG_ + gc]
                             + m2 * Uh_b[2 * CG_ + gc];
        }
        float ig = 1.0f / (1.0f + expf(-g[0]));
        float og = 1.0f / (1.0f + expf(-g[1]));
        float ug = tanhf(g[2]);
        float c = ig * ug;
        if (m0 != 0.0f) c += (1.0f / (1.0f + expf(-g[3]))) * c_s[((size_t)cix[bb][0] * CB + b) * CH + hh];
        if (m1 != 0.0f) c += (1.0f / (1.0f + expf(-g[4]))) * c_s[((size_t)cix[bb][1] * CB + b) * CH + hh];
        if (m2 != 0.0f) c += (1.0f / (1.0f + expf(-g[5]))) * c_s[((size_t)cix[bb][2] * CB + b) * CH + hh];
        float h = og * tanhf(c);
        h_s[((size_t)t * CB + b) * CH + hh] = h;
        c_s[((size_t)t * CB + b) * CH + hh] = c;
        if (t == CN - 1) out[(size_t)b * CH + hh] = h;
    }
}

__global__ void ws_report(float* out, int n, float val) {
    int i = blockIdx.x * blockDim.x + threadIdx.x;
    if (i < n) out[i] = val;
}

// ---------------------------------------------------------------------------
extern "C" void kernel_launch(void* const* d_in, const int* in_sizes, int n_in,
                              void* d_out, int out_size, void* d_ws, size_t ws_size,
                              hipStream_t stream) {
    float* outp = (float*)d_out;

    const int expect_sizes[7] = {65536, 196608, 8192000, 393216, 1536, 1179648, 4608};
    int bad = -1;
    if (n_in != 7) bad = 7;
    else for (int i = 0; i < 7; ++i) if (in_sizes[i] != expect_sizes[i]) { bad = i; break; }
    if (bad >= 0) {
        ws_report<<<(out_size + 255) / 256, 256, 0, stream>>>(outp, out_size, 1000.0f + bad);
        return;
    }

    const int*   node_ids = (const int*)d_in[0];
    const int*   children = (const int*)d_in[1];
    const float* emb      = (const float*)d_in[2];
    const float* Wx_w     = (const float*)d_in[3];
    const float* Wx_b     = (const float*)d_in[4];
    const float* Uh_w     = (const float*)d_in[5];
    const float* Uh_b     = (const float*)d_in[6];

    const size_t w_plane  = (size_t)CG_ * KTOT * 2;   //  3,145,728 B
    const size_t h_plane  = (size_t)CN * CB * CH * 2; // 33,554,432 B (bf16)
    const size_t c_bytes  = (size_t)CN * CB * CH * 4; // 67,108,864 B
    const size_t need_mfma = 2 * w_plane + 2 * h_plane + c_bytes;  // 140,509,184 (proven)
    const size_t need_plain = 2 * c_bytes;                          // 134,217,728

    if (ws_size >= need_mfma) {
        char* w = (char*)d_ws;
        unsigned short* Whi = (unsigned short*)w;
        unsigned short* Wlo = (unsigned short*)(w + w_plane);
        unsigned short* hhi = (unsigned short*)(w + 2 * w_plane);
        unsigned short* hlo = (unsigned short*)(w + 2 * w_plane + h_plane);
        float*          csb = (float*)(w + 2 * w_plane + 2 * h_plane);

        prep_w<<<dim3(CG_), dim3(256), 0, stream>>>(Wx_w, Uh_w, Whi, Wlo);
        for (int t = 0; t < CN; ++t)
            tree_step_mfma<<<dim3(256), dim3(768), 0, stream>>>(
                node_ids, children, emb, Whi, Wlo, Wx_b, Uh_b,
                hhi, hlo, csb, outp, t);
    } else if (ws_size >= need_plain) {
        float* h_s = (float*)d_ws;
        float* c_s = (float*)((char*)d_ws + c_bytes);
        for (int t = 0; t < CN; ++t)
            tree_step<<<dim3(256), dim3(512), 0, stream>>>(
                node_ids, children, emb, Wx_w, Wx_b, Uh_w, Uh_b,
                h_s, c_s, outp, t);
    } else {
        ws_report<<<(out_size + 255) / 256, 256, 0, stream>>>(
            outp, out_size, (float)(ws_size >> 20));
    }
}

// Round 12
// 4480.107 us; speedup vs baseline: 1.0691x; 1.0691x over previous
//
#include <hip/hip_runtime.h>
#include <hip/hip_bf16.h>

#define CB 256      // batch
#define CN 256      // nodes
#define CK 3        // children per node
#define CE 256      // embedding dim
#define CH 256      // hidden dim
#define CG_ 1536    // gates = 6*CH
#define KTOT 1024   // E + K*H
#define APAD 8
#define ASTR (KTOT + APAD)   // LDS A row stride (shorts) = 1032 (2064 B)

typedef __attribute__((ext_vector_type(8))) short short8v;          // 8 bf16
typedef __attribute__((ext_vector_type(4))) float float4v;          // MFMA C/D
typedef __attribute__((ext_vector_type(4))) unsigned int uint4v;
typedef __attribute__((ext_vector_type(4))) unsigned short ushort4v;
typedef unsigned int u32;
typedef unsigned long long u64;

__device__ __forceinline__ unsigned short f2bfu(float v) {
    __hip_bfloat16 h = __float2bfloat16(v);
    return __builtin_bit_cast(unsigned short, h);
}
__device__ __forceinline__ float bfu2f(unsigned short u) {
    __hip_bfloat16 h = __builtin_bit_cast(__hip_bfloat16, u);
    return __bfloat162float(h);
}

// ---------------------------------------------------------------------------
// Prep (verified r8-r11): split virtual W = [Wx_w ; Uh_w] (1024 x 1536) into
// K-major bf16 hi/lo planes [g][k].
// ---------------------------------------------------------------------------
__global__ __launch_bounds__(256) void prep_w(
    const float* __restrict__ Wx_w, const float* __restrict__ Uh_w,
    unsigned short* __restrict__ Whi, unsigned short* __restrict__ Wlo)
{
    const int g = blockIdx.x;
    for (int k = threadIdx.x; k < KTOT; k += 256) {
        float w = (k < CE) ? Wx_w[(size_t)k * CG_ + g]
                           : Uh_w[(size_t)(k - CE) * CG_ + g];
        unsigned short hi = f2bfu(w);
        Whi[(size_t)g * KTOT + k] = hi;
        Wlo[(size_t)g * KTOT + k] = f2bfu(w - bfu2f(hi));
    }
}

// ---------------------------------------------------------------------------
// PERSISTENT cooperative scan. 256 blocks x 768 threads (12 waves), 1/CU.
// Key structural changes vs r10 (mechanism: per-step kernel relaunch
// invalidates L2 -> 100 MB/step of B-panel re-streamed from L3; r9 showed
// grid.sync+threadfence is worse, full L2 flush):
//  - B panel (each thread's 32 x 16B slice = 128 VGPR) loaded ONCE into
//    registers before the t-loop: zero W traffic during the scan.
//  - h state packed u32 (hi16|lo16 bf16 planes of the r8-verified split);
//    ALL cross-block state (h_pk, c_s) accessed via agent-scope atomics
//    (sc1: bypass non-coherent per-XCD L2, coherent at MALL). No fences.
//  - barrier: per-block flag (stride-64B) + 256-thread poll +
//    __syncthreads_and. No threadfence, no L2 writeback/invalidate.
// ---------------------------------------------------------------------------
__global__ __launch_bounds__(768, 3) void tree_scan_pers(
    const int* __restrict__ node_ids,          // [B][N]
    const int* __restrict__ children,          // [B][N][K]
    const float* __restrict__ emb,             // [V][E]
    const unsigned short* __restrict__ Whi,    // [1536][1024]
    const unsigned short* __restrict__ Wlo,    // [1536][1024]
    const float* __restrict__ Wx_b,            // [G]
    const float* __restrict__ Uh_b,            // [K][G]
    u32* __restrict__ h_pk,                    // [N][B][H] u32 (hi16|lo16)
    float* __restrict__ c_s,                   // [N][B][H] f32
    u32* __restrict__ flags,                   // [256*16] u32, zeroed
    float* __restrict__ out)                   // [B][H] f32
{
    const int tid = threadIdx.x;
    const int bid = blockIdx.x;
    const int hi  = bid & 15;
    const int bi  = bid >> 4;
    const int b0  = bi * 16;
    const int hh0 = hi * 16;

    __shared__ unsigned short Ahi[16][ASTR];   // 33,024 B
    __shared__ unsigned short Alo[16][ASTR];   // 33,024 B
    __shared__ float part[4][6][16][17];       // 26,112 B
    __shared__ int   nid[16];
    __shared__ float msk[16][3];
    __shared__ int   cix[16][3];

    const int wv    = tid >> 6;                // 0..11
    const int l     = tid & 63;
    const int np    = wv % 3;                  // N-pair (2 q-tiles)
    const int kq    = wv / 3;                  // K-quarter
    const int lan15 = l & 15;
    const int k8    = (l >> 4) * 8;

    // ---- B panel -> registers, once (128 VGPR/thread) ----
    size_t bbase0 = (size_t)((np * 2 + 0) * CH + hh0 + lan15) * KTOT + k8;
    size_t bbase1 = (size_t)((np * 2 + 1) * CH + hh0 + lan15) * KTOT + k8;
    short8v Bh[8][2], Bl[8][2];
    #pragma unroll
    for (int ci = 0; ci < 8; ++ci) {
        const int kbg = (kq * 8 + ci) * 32;
        Bh[ci][0] = *(const short8v*)(Whi + bbase0 + kbg);
        Bh[ci][1] = *(const short8v*)(Whi + bbase1 + kbg);
        Bl[ci][0] = *(const short8v*)(Wlo + bbase0 + kbg);
        Bl[ci][1] = *(const short8v*)(Wlo + bbase1 + kbg);
    }

    for (int t = 0; t < CN; ++t) {
        if (tid < 16) nid[tid] = node_ids[(size_t)(b0 + tid) * CN + t];
        if (tid < 48) {
            int lb = tid / 3, k = tid - lb * 3;
            int raw = children[((size_t)(b0 + lb) * CN + t) * CK + k];
            int v = raw < t;
            msk[lb][k] = v ? 1.0f : 0.0f;
            cix[lb][k] = v ? raw : 0;
        }
        __syncthreads();

        // stage x: 16 rows x 64 float4 chunks; split hi/lo in-register
        for (int idx = tid; idx < 1024; idx += 768) {
            int lb = idx >> 6, c4 = idx & 63;
            float4v v = *(const float4v*)(emb + (size_t)nid[lb] * CE + c4 * 4);
            ushort4v h4, l4;
            #pragma unroll
            for (int j = 0; j < 4; ++j) {
                unsigned short hb = f2bfu(v[j]);
                h4[j] = hb;
                l4[j] = f2bfu(v[j] - bfu2f(hb));
            }
            *(ushort4v*)&Ahi[lb][c4 * 4] = h4;
            *(ushort4v*)&Alo[lb][c4 * 4] = l4;
        }
        // stage h: 48 (lb,k) rows x 128 8B-chunks of packed u32 pairs,
        // agent-scope loads (coherent, L2-bypassing)
        for (int idx = tid; idx < 6144; idx += 768) {
            int r  = idx >> 7;                 // 0..47
            int ch = idx & 127;                // u64 chunk -> cols 2ch, 2ch+1
            int lb = r / 3, k = r - lb * 3;
            u64 v = 0;
            if (msk[lb][k] != 0.0f) {
                const u64* src = (const u64*)(h_pk
                    + ((size_t)cix[lb][k] * CB + (b0 + lb)) * CH + 2 * ch);
                v = __hip_atomic_load(src, __ATOMIC_RELAXED, __HIP_MEMORY_SCOPE_AGENT);
            }
            u32 e0 = (u32)v, e1 = (u32)(v >> 32);
            int cc = CE + k * CH + 2 * ch;
            *(u32*)&Ahi[lb][cc] = (e0 >> 16) | (e1 & 0xffff0000u);
            *(u32*)&Alo[lb][cc] = (e0 & 0xffffu) | (e1 << 16);
        }
        __syncthreads();

        // MFMA bf16x3: B from registers, A from LDS
        {
            float4v acc[2][3];
            #pragma unroll
            for (int a = 0; a < 2; ++a)
                #pragma unroll
                for (int b = 0; b < 3; ++b)
                    acc[a][b] = (float4v){0.f, 0.f, 0.f, 0.f};

            #pragma unroll
            for (int ci = 0; ci < 8; ++ci) {
                const int kb = (kq * 8 + ci) * 32 + k8;
                short8v ahi = *(const short8v*)&Ahi[lan15][kb];
                short8v alo = *(const short8v*)&Alo[lan15][kb];
                #pragma unroll
                for (int t2 = 0; t2 < 2; ++t2) {
                    acc[t2][0] = __builtin_amdgcn_mfma_f32_16x16x32_bf16(ahi, Bh[ci][t2], acc[t2][0], 0, 0, 0);
                    acc[t2][1] = __builtin_amdgcn_mfma_f32_16x16x32_bf16(ahi, Bl[ci][t2], acc[t2][1], 0, 0, 0);
                    acc[t2][2] = __builtin_amdgcn_mfma_f32_16x16x32_bf16(alo, Bh[ci][t2], acc[t2][2], 0, 0, 0);
                }
            }
            #pragma unroll
            for (int t2 = 0; t2 < 2; ++t2)
                #pragma unroll
                for (int r = 0; r < 4; ++r)
                    part[kq][np * 2 + t2][(l >> 4) * 4 + r][lan15] =
                        acc[t2][0][r] + acc[t2][1][r] + acc[t2][2][r];
        }
        __syncthreads();

        // cell phase (r7-verified math); state via agent-scope atomics
        if (tid < 256) {
            const int bb = tid >> 4, j2 = tid & 15;
            const int b = b0 + bb, hh = hh0 + j2;
            const float m0 = msk[bb][0], m1 = msk[bb][1], m2 = msk[bb][2];
            float g[6];
            #pragma unroll
            for (int q = 0; q < 6; ++q) {
                int gc = q * CH + hh;
                g[q] = part[0][q][bb][j2] + part[1][q][bb][j2]
                     + part[2][q][bb][j2] + part[3][q][bb][j2]
                     + Wx_b[gc] + m0 * Uh_b[gc] + m1 * Uh_b[CG_ + gc]
                                + m2 * Uh_b[2 * CG_ + gc];
            }
            float ig = 1.0f / (1.0f + expf(-g[0]));
            float og = 1.0f / (1.0f + expf(-g[1]));
            float ug = tanhf(g[2]);
            float c = ig * ug;
            if (m0 != 0.0f) c += (1.0f / (1.0f + expf(-g[3]))) *
                __hip_atomic_load(&c_s[((size_t)cix[bb][0] * CB + b) * CH + hh],
                                  __ATOMIC_RELAXED, __HIP_MEMORY_SCOPE_AGENT);
            if (m1 != 0.0f) c += (1.0f / (1.0f + expf(-g[4]))) *
                __hip_atomic_load(&c_s[((size_t)cix[bb][1] * CB + b) * CH + hh],
                                  __ATOMIC_RELAXED, __HIP_MEMORY_SCOPE_AGENT);
            if (m2 != 0.0f) c += (1.0f / (1.0f + expf(-g[5]))) *
                __hip_atomic_load(&c_s[((size_t)cix[bb][2] * CB + b) * CH + hh],
                                  __ATOMIC_RELAXED, __HIP_MEMORY_SCOPE_AGENT);
            float h = og * tanhf(c);
            const size_t hx = ((size_t)t * CB + b) * CH + hh;
            unsigned short hb = f2bfu(h);
            u32 hp = ((u32)hb << 16) | (u32)f2bfu(h - bfu2f(hb));
            __hip_atomic_store(&h_pk[hx], hp, __ATOMIC_RELAXED, __HIP_MEMORY_SCOPE_AGENT);
            __hip_atomic_store(&c_s[hx], c, __ATOMIC_RELAXED, __HIP_MEMORY_SCOPE_AGENT);
            if (t == CN - 1) out[(size_t)b * CH + hh] = h;
        }

        if (t == CN - 1) break;                // no barrier after last step

        // ---- light grid barrier: flag store + poll (no device fence) ----
        __syncthreads();                       // drains all waves' vm stores
        if (tid == 0)
            __hip_atomic_store(&flags[bid * 16], (u32)(t + 1),
                               __ATOMIC_RELAXED, __HIP_MEMORY_SCOPE_AGENT);
        for (;;) {
            int ok = 1;
            if (tid < 256)
                ok = (__hip_atomic_load(&flags[tid * 16], __ATOMIC_RELAXED,
                                        __HIP_MEMORY_SCOPE_AGENT) >= (u32)(t + 1));
            if (__syncthreads_and(ok)) break;
            __builtin_amdgcn_s_sleep(2);
        }
    }
}

// ---------------------------------------------------------------------------
// Fallback: r10-verified per-step MFMA kernel (used only if coop launch fails).
// ---------------------------------------------------------------------------
__global__ __launch_bounds__(768) void tree_step_mfma(
    const int* __restrict__ node_ids, const int* __restrict__ children,
    const float* __restrict__ emb,
    const unsigned short* __restrict__ Whi, const unsigned short* __restrict__ Wlo,
    const float* __restrict__ Wx_b, const float* __restrict__ Uh_b,
    unsigned short* __restrict__ h_hi, unsigned short* __restrict__ h_lo,
    float* __restrict__ c_s, float* __restrict__ out, const int t)
{
    const int tid = threadIdx.x;
    const int xcd  = blockIdx.x & 7;
    const int bidx = blockIdx.x >> 3;
    const int hi   = xcd * 2 + (bidx & 1);
    const int bi   = bidx >> 1;
    const int b0   = bi * 16;
    const int hh0  = hi * 16;

    __shared__ unsigned short Ahi[16][ASTR];
    __shared__ unsigned short Alo[16][ASTR];
    __shared__ float part[4][6][16][17];
    __shared__ int   nid[16];
    __shared__ float msk[16][3];
    __shared__ int   cix[16][3];

    const int wv    = tid >> 6;
    const int l     = tid & 63;
    const int np    = wv % 3;
    const int kq    = wv / 3;
    const int lan15 = l & 15;
    const int k8    = (l >> 4) * 8;

    if (tid < 16) nid[tid] = node_ids[(size_t)(b0 + tid) * CN + t];
    if (tid < 48) {
        int lb = tid / 3, k = tid - lb * 3;
        int raw = children[((size_t)(b0 + lb) * CN + t) * CK + k];
        int v = raw < t;
        msk[lb][k] = v ? 1.0f : 0.0f;
        cix[lb][k] = v ? raw : 0;
    }
    __syncthreads();

    for (int idx = tid; idx < 1024; idx += 768) {
        int lb = idx >> 6, c4 = idx & 63;
        float4v v = *(const float4v*)(emb + (size_t)nid[lb] * CE + c4 * 4);
        ushort4v h4, l4;
        #pragma unroll
        for (int j = 0; j < 4; ++j) {
            unsigned short hb = f2bfu(v[j]);
            h4[j] = hb;
            l4[j] = f2bfu(v[j] - bfu2f(hb));
        }
        *(ushort4v*)&Ahi[lb][c4 * 4] = h4;
        *(ushort4v*)&Alo[lb][c4 * 4] = l4;
    }
    for (int idx = tid; idx < 3072; idx += 768) {
        int r  = idx >> 6;
        int c  = idx & 63;
        int pl = c >> 5;
        int ch = c & 31;
        int lb = r / 3, k = r - lb * 3;
        uint4v val = (uint4v){0u, 0u, 0u, 0u};
        if (msk[lb][k] != 0.0f) {
            const unsigned short* src = (pl ? h_lo : h_hi)
                + ((size_t)cix[lb][k] * CB + (b0 + lb)) * CH + ch * 8;
            val = *(const uint4v*)src;
        }
        unsigned short* dst = (pl ? &Alo[lb][CE + k * CH + ch * 8]
                                  : &Ahi[lb][CE + k * CH + ch * 8]);
        *(uint4v*)dst = val;
    }
    __syncthreads();

    {
        float4v acc[2][3];
        #pragma unroll
        for (int a = 0; a < 2; ++a)
            #pragma unroll
            for (int b = 0; b < 3; ++b)
                acc[a][b] = (float4v){0.f, 0.f, 0.f, 0.f};
        size_t bbase0 = (size_t)((np * 2 + 0) * CH + hh0 + lan15) * KTOT + k8;
        size_t bbase1 = (size_t)((np * 2 + 1) * CH + hh0 + lan15) * KTOT + k8;
        #pragma unroll
        for (int ci = 0; ci < 8; ++ci) {
            const int kb = (kq * 8 + ci) * 32 + k8;
            const int kbg = (kq * 8 + ci) * 32;
            short8v ahi = *(const short8v*)&Ahi[lan15][kb];
            short8v alo = *(const short8v*)&Alo[lan15][kb];
            short8v bh0 = *(const short8v*)(Whi + bbase0 + kbg);
            short8v bh1 = *(const short8v*)(Whi + bbase1 + kbg);
            short8v bl0 = *(const short8v*)(Wlo + bbase0 + kbg);
            short8v bl1 = *(const short8v*)(Wlo + bbase1 + kbg);
            acc[0][0] = __builtin_amdgcn_mfma_f32_16x16x32_bf16(ahi, bh0, acc[0][0], 0, 0, 0);
            acc[0][1] = __builtin_amdgcn_mfma_f32_16x16x32_bf16(ahi, bl0, acc[0][1], 0, 0, 0);
            acc[0][2] = __builtin_amdgcn_mfma_f32_16x16x32_bf16(alo, bh0, acc[0][2], 0, 0, 0);
            acc[1][0] = __builtin_amdgcn_mfma_f32_16x16x32_bf16(ahi, bh1, acc[1][0], 0, 0, 0);
            acc[1][1] = __builtin_amdgcn_mfma_f32_16x16x32_bf16(ahi, bl1, acc[1][1], 0, 0, 0);
            acc[1][2] = __builtin_amdgcn_mfma_f32_16x16x32_bf16(alo, bh1, acc[1][2], 0, 0, 0);
        }
        #pragma unroll
        for (int t2 = 0; t2 < 2; ++t2)
            #pragma unroll
            for (int r = 0; r < 4; ++r)
                part[kq][np * 2 + t2][(l >> 4) * 4 + r][lan15] =
                    acc[t2][0][r] + acc[t2][1][r] + acc[t2][2][r];
    }
    __syncthreads();

    if (tid < 256) {
        const int bb = tid >> 4, j2 = tid & 15;
        const int b = b0 + bb, hh = hh0 + j2;
        const float m0 = msk[bb][0], m1 = msk[bb][1], m2 = msk[bb][2];
        float g[6];
        #pragma unroll
        for (int q = 0; q < 6; ++q) {
            int gc = q * CH + hh;
            g[q] = part[0][q][bb][j2] + part[1][q][bb][j2]
                 + part[2][q][bb][j2] + part[3][q][bb][j2]
                 + Wx_b[gc] + m0 * Uh_b[gc] + m1 * Uh_b[CG_ + gc]
                            + m2 * Uh_b[2 * CG_ + gc];
        }
        float ig = 1.0f / (1.0f + expf(-g[0]));
        float og = 1.0f / (1.0f + expf(-g[1]));
        float ug = tanhf(g[2]);
        float c = ig * ug;
        if (m0 != 0.0f) c += (1.0f / (1.0f + expf(-g[3]))) * c_s[((size_t)cix[bb][0] * CB + b) * CH + hh];
        if (m1 != 0.0f) c += (1.0f / (1.0f + expf(-g[4]))) * c_s[((size_t)cix[bb][1] * CB + b) * CH + hh];
        if (m2 != 0.0f) c += (1.0f / (1.0f + expf(-g[5]))) * c_s[((size_t)cix[bb][2] * CB + b) * CH + hh];
        float h = og * tanhf(c);
        const size_t hx = ((size_t)t * CB + b) * CH + hh;
        unsigned short hb = f2bfu(h);
        h_hi[hx] = hb;
        h_lo[hx] = f2bfu(h - bfu2f(hb));
        c_s[hx] = c;
        if (t == CN - 1) out[(size_t)b * CH + hh] = h;
    }
}

__global__ void ws_report(float* out, int n, float val) {
    int i = blockIdx.x * blockDim.x + threadIdx.x;
    if (i < n) out[i] = val;
}

// ---------------------------------------------------------------------------
extern "C" void kernel_launch(void* const* d_in, const int* in_sizes, int n_in,
                              void* d_out, int out_size, void* d_ws, size_t ws_size,
                              hipStream_t stream) {
    float* outp = (float*)d_out;

    const int expect_sizes[7] = {65536, 196608, 8192000, 393216, 1536, 1179648, 4608};
    int bad = -1;
    if (n_in != 7) bad = 7;
    else for (int i = 0; i < 7; ++i) if (in_sizes[i] != expect_sizes[i]) { bad = i; break; }
    if (bad >= 0) {
        ws_report<<<(out_size + 255) / 256, 256, 0, stream>>>(outp, out_size, 1000.0f + bad);
        return;
    }

    const int*   node_ids = (const int*)d_in[0];
    const int*   children = (const int*)d_in[1];
    const float* emb      = (const float*)d_in[2];
    const float* Wx_w     = (const float*)d_in[3];
    const float* Wx_b     = (const float*)d_in[4];
    const float* Uh_w     = (const float*)d_in[5];
    const float* Uh_b     = (const float*)d_in[6];

    const size_t w_plane  = (size_t)CG_ * KTOT * 2;       //  3,145,728 B
    const size_t st_words = (size_t)CN * CB * CH;         // 16,777,216 elems
    const size_t flags_sz = 256 * 16 * sizeof(u32);       // 16 KB
    // persistent carve: Whi | Wlo | h_pk(u32) | c_s(f32) | flags
    const size_t need_pers = 2 * w_plane + st_words * 4 + st_words * 4 + flags_sz; // ~134.3 MB
    // fallback carve: Whi | Wlo | h_hi | h_lo | c_s  (proven 140.5 MB in r8-r11)
    const size_t need_step = 2 * w_plane + st_words * 2 * 2 + st_words * 4;

    if (ws_size >= need_pers) {
        char* w = (char*)d_ws;
        unsigned short* Whi = (unsigned short*)w;
        unsigned short* Wlo = (unsigned short*)(w + w_plane);
        u32*   hpk  = (u32*)(w + 2 * w_plane);
        float* csb  = (float*)(w + 2 * w_plane + st_words * 4);
        u32*   flg  = (u32*)(w + 2 * w_plane + 2 * st_words * 4);

        prep_w<<<dim3(CG_), dim3(256), 0, stream>>>(Wx_w, Uh_w, Whi, Wlo);
        hipMemsetAsync(flg, 0, flags_sz, stream);

        void* args[] = { (void*)&node_ids, (void*)&children, (void*)&emb,
                         (void*)&Whi, (void*)&Wlo, (void*)&Wx_b, (void*)&Uh_b,
                         (void*)&hpk, (void*)&csb, (void*)&flg, (void*)&outp };
        hipError_t e = hipLaunchCooperativeKernel((const void*)tree_scan_pers,
                                                  dim3(256), dim3(768), args, 0, stream);
        if (e == hipSuccess) return;
        // else fall through to per-step path
    }
    if (ws_size >= need_step) {
        char* w = (char*)d_ws;
        unsigned short* Whi = (unsigned short*)w;
        unsigned short* Wlo = (unsigned short*)(w + w_plane);
        unsigned short* hhi = (unsigned short*)(w + 2 * w_plane);
        unsigned short* hlo = (unsigned short*)(w + 2 * w_plane + st_words * 2);
        float*          csb = (float*)(w + 2 * w_plane + 2 * st_words * 2);

        prep_w<<<dim3(CG_), dim3(256), 0, stream>>>(Wx_w, Uh_w, Whi, Wlo);
        for (int t = 0; t < CN; ++t)
            tree_step_mfma<<<dim3(256), dim3(768), 0, stream>>>(
                node_ids, children, emb, Whi, Wlo, Wx_b, Uh_b,
                hhi, hlo, csb, outp, t);
    } else {
        ws_report<<<(out_size + 255) / 256, 256, 0, stream>>>(
            outp, out_size, (float)(ws_size >> 20));
    }
}

// Round 14
// 4307.559 us; speedup vs baseline: 1.1120x; 1.0401x over previous
//
#include <hip/hip_runtime.h>
#include <hip/hip_bf16.h>

#define CB 256      // batch
#define CN 256      // nodes
#define CK 3        // children per node
#define CE 256      // embedding dim
#define CH 256      // hidden dim
#define CG_ 1536    // gates = 6*CH
#define KTOT 1024   // E + K*H
#define APAD 8
#define ASTR (KTOT + APAD)   // LDS A row stride (shorts) = 1032 (2064 B)

typedef __attribute__((ext_vector_type(8))) short short8v;          // 8 bf16
typedef __attribute__((ext_vector_type(4))) float float4v;          // MFMA C/D
typedef __attribute__((ext_vector_type(4))) unsigned int uint4v;
typedef __attribute__((ext_vector_type(4))) unsigned short ushort4v;
typedef unsigned int u32;
typedef unsigned long long u64;
typedef unsigned short u16;

__device__ __forceinline__ u16 f2bfu(float v) {
    __hip_bfloat16 h = __float2bfloat16(v);
    return __builtin_bit_cast(u16, h);
}
__device__ __forceinline__ float bfu2f(u16 u) {
    __hip_bfloat16 h = __builtin_bit_cast(__hip_bfloat16, u);
    return __bfloat162float(h);
}

// ---------------------------------------------------------------------------
// Prep (verified r8-r12): split virtual W = [Wx_w ; Uh_w] (1024 x 1536) into
// K-major bf16 hi/lo planes [g][k].
// ---------------------------------------------------------------------------
__global__ __launch_bounds__(256) void prep_w(
    const float* __restrict__ Wx_w, const float* __restrict__ Uh_w,
    u16* __restrict__ Whi, u16* __restrict__ Wlo)
{
    const int g = blockIdx.x;
    for (int k = threadIdx.x; k < KTOT; k += 256) {
        float w = (k < CE) ? Wx_w[(size_t)k * CG_ + g]
                           : Uh_w[(size_t)(k - CE) * CG_ + g];
        u16 hi = f2bfu(w);
        Whi[(size_t)g * KTOT + k] = hi;
        Wlo[(size_t)g * KTOT + k] = f2bfu(w - bfu2f(hi));
    }
}

// ---------------------------------------------------------------------------
// Level schedule build (1 block x 256 threads, thread = batch b).
// level(t) = 0 if no valid child else 1+max(level(child)). Then histogram,
// prefix, scatter (b,t) u16 entries into level-bucketed worklist.
// NOTE r13 bug: (b=255,t=255) encodes to 0xFFFF which collided with the
// in-kernel padding sentinel -> root of tree 255 silently skipped. Fixed by
// carrying an explicit per-row validity flag instead of a sentinel value.
// ---------------------------------------------------------------------------
__global__ __launch_bounds__(256) void build_sched(
    const int* __restrict__ children,
    u16* __restrict__ wl,             // [65536] (b<<8)|t
    u32* __restrict__ lvl_start,      // [256]
    u32* __restrict__ lvl_cnt,        // [256]
    u32* __restrict__ nlev)           // [1]
{
    __shared__ unsigned char lvl[CB][CN];   // 64 KB
    __shared__ u32 cnt[CN];
    __shared__ u32 pos[CN];
    const int b = threadIdx.x;

    for (int t = 0; t < CN; ++t) {
        int lv = 0;
        #pragma unroll
        for (int k = 0; k < CK; ++k) {
            int raw = children[((size_t)b * CN + t) * CK + k];
            if (raw < t) { int cl = (int)lvl[b][raw] + 1; if (cl > lv) lv = cl; }
        }
        lvl[b][t] = (unsigned char)lv;
    }
    cnt[b] = 0;
    __syncthreads();
    for (int t = 0; t < CN; ++t) atomicAdd(&cnt[lvl[b][t]], 1u);
    __syncthreads();
    if (b == 0) {
        u32 acc = 0, nl = 0;
        for (int L = 0; L < CN; ++L) {
            pos[L] = acc;
            if (cnt[L]) nl = (u32)L + 1;
            acc += cnt[L];
        }
        *nlev = nl;
    }
    __syncthreads();
    lvl_cnt[b]   = cnt[b];
    lvl_start[b] = pos[b];
    __syncthreads();                        // exports done before pos mutates
    for (int t = 0; t < CN; ++t) {
        int L = lvl[b][t];
        u32 p = atomicAdd(&pos[L], 1u);
        wl[p] = (u16)((b << 8) | t);
    }
}

// ---------------------------------------------------------------------------
// LEVEL-SCHEDULED persistent cooperative scan. 256 blocks x 768 threads.
// Dependency depth ~25 (not 256): grid barriers 255 -> ~24; each block
// streams many independent 16-row tasks per level. Per-task machinery
// identical to r12 (verified): A=[x|masked child h] hi/lo bf16 in LDS,
// bf16x3 MFMA, r7-verified cell math, agent-scope atomics for cross-block
// state, flag barrier per level. Row validity carried explicitly in rval[]
// (r13's 0xFFFF sentinel collided with real task (255,255)).
// ---------------------------------------------------------------------------
__global__ __launch_bounds__(768, 3) void tree_scan_lvl(
    const int* __restrict__ node_ids,          // [B][N]
    const int* __restrict__ children,          // [B][N][K]
    const float* __restrict__ emb,             // [V][E]
    const u16* __restrict__ Whi,               // [1536][1024]
    const u16* __restrict__ Wlo,               // [1536][1024]
    const float* __restrict__ Wx_b,            // [G]
    const float* __restrict__ Uh_b,            // [K][G]
    u32* __restrict__ h_pk,                    // [N][B][H] u32 (hi16|lo16)
    float* __restrict__ c_s,                   // [N][B][H] f32
    u32* __restrict__ flags,                   // [256*16], zeroed per call
    const u16* __restrict__ wl,                // [65536]
    const u32* __restrict__ lvl_start,         // [256]
    const u32* __restrict__ lvl_cnt,           // [256]
    const u32* __restrict__ nlev_p,            // [1]
    float* __restrict__ out)                   // [B][H] f32
{
    const int tid = threadIdx.x;
    const int bid = blockIdx.x;
    const int hi  = 2 * (bid & 7) + ((bid >> 3) & 1);   // XCD-affine
    const int sub = bid >> 4;                            // 0..15
    const int hh0 = hi * 16;

    __shared__ u16   Ahi[16][ASTR];            // 33,024 B
    __shared__ u16   Alo[16][ASTR];            // 33,024 B
    __shared__ float part[4][6][16][17];       // 26,112 B
    __shared__ int   nid[16], brow[16], trow[16];
    __shared__ unsigned char rval[16];
    __shared__ float msk[16][3];
    __shared__ int   cix[16][3];

    const int wv    = tid >> 6;                // 0..11
    const int l     = tid & 63;
    const int np    = wv % 3;                  // N-pair (2 q-tiles)
    const int kq    = wv / 3;                  // K-quarter
    const int lan15 = l & 15;
    const int k8    = (l >> 4) * 8;

    // B panel -> registers once (r12 pattern)
    size_t bbase0 = (size_t)((np * 2 + 0) * CH + hh0 + lan15) * KTOT + k8;
    size_t bbase1 = (size_t)((np * 2 + 1) * CH + hh0 + lan15) * KTOT + k8;
    short8v Bh[8][2], Bl[8][2];
    #pragma unroll
    for (int ci = 0; ci < 8; ++ci) {
        const int kbg = (kq * 8 + ci) * 32;
        Bh[ci][0] = *(const short8v*)(Whi + bbase0 + kbg);
        Bh[ci][1] = *(const short8v*)(Whi + bbase1 + kbg);
        Bl[ci][0] = *(const short8v*)(Wlo + bbase0 + kbg);
        Bl[ci][1] = *(const short8v*)(Wlo + bbase1 + kbg);
    }

    const u32 NL = *nlev_p;

    for (u32 L = 0; L < NL; ++L) {
        const u32 lcnt   = lvl_cnt[L];
        const u32 lst    = lvl_start[L];
        const u32 nchunk = (lcnt + 15) >> 4;

        for (u32 ck = sub; ck < nchunk; ck += 16) {
            // per-task row setup (wave 0; in-wave program order covers the
            // rval/brow -> tid<48 dependency)
            if (tid < 16) {
                u32 i = ck * 16 + (u32)tid;
                int valid = (i < lcnt);
                u16 e = valid ? wl[lst + i] : (u16)0;
                rval[tid] = (unsigned char)valid;
                int b_ = valid ? (e >> 8) : 0;
                int t_ = valid ? (e & 0xFF) : 0;
                brow[tid] = b_;
                trow[tid] = t_;
                nid[tid]  = node_ids[(size_t)b_ * CN + t_];
            }
            if (tid < 48) {
                int lb = tid / 3, k = tid - lb * 3;
                int b_ = brow[lb], t_ = trow[lb];
                int raw = children[((size_t)b_ * CN + t_) * CK + k];
                int v = (raw < t_) && rval[lb];
                msk[lb][k] = v ? 1.0f : 0.0f;
                cix[lb][k] = v ? raw : 0;
            }
            __syncthreads();

            // stage x: 16 rows x 64 float4 chunks; split hi/lo in-register
            for (int idx = tid; idx < 1024; idx += 768) {
                int lb = idx >> 6, c4 = idx & 63;
                float4v v = *(const float4v*)(emb + (size_t)nid[lb] * CE + c4 * 4);
                ushort4v h4, l4;
                #pragma unroll
                for (int j = 0; j < 4; ++j) {
                    u16 hb = f2bfu(v[j]);
                    h4[j] = hb;
                    l4[j] = f2bfu(v[j] - bfu2f(hb));
                }
                *(ushort4v*)&Ahi[lb][c4 * 4] = h4;
                *(ushort4v*)&Alo[lb][c4 * 4] = l4;
            }
            // stage h: 48 (lb,k) rows x 128 u64 chunks of packed u32 pairs
            for (int idx = tid; idx < 6144; idx += 768) {
                int r  = idx >> 7;             // 0..47
                int ch = idx & 127;
                int lb = r / 3, k = r - lb * 3;
                u64 v = 0;
                if (msk[lb][k] != 0.0f) {
                    const u64* src = (const u64*)(h_pk
                        + ((size_t)cix[lb][k] * CB + brow[lb]) * CH + 2 * ch);
                    v = __hip_atomic_load(src, __ATOMIC_RELAXED, __HIP_MEMORY_SCOPE_AGENT);
                }
                u32 e0 = (u32)v, e1 = (u32)(v >> 32);
                int cc = CE + k * CH + 2 * ch;
                *(u32*)&Ahi[lb][cc] = (e0 >> 16) | (e1 & 0xffff0000u);
                *(u32*)&Alo[lb][cc] = (e0 & 0xffffu) | (e1 << 16);
            }
            __syncthreads();

            // MFMA bf16x3 (r12-verified)
            {
                float4v acc[2][3];
                #pragma unroll
                for (int a = 0; a < 2; ++a)
                    #pragma unroll
                    for (int b2 = 0; b2 < 3; ++b2)
                        acc[a][b2] = (float4v){0.f, 0.f, 0.f, 0.f};

                #pragma unroll
                for (int ci = 0; ci < 8; ++ci) {
                    const int kb = (kq * 8 + ci) * 32 + k8;
                    short8v ahi = *(const short8v*)&Ahi[lan15][kb];
                    short8v alo = *(const short8v*)&Alo[lan15][kb];
                    #pragma unroll
                    for (int t2 = 0; t2 < 2; ++t2) {
                        acc[t2][0] = __builtin_amdgcn_mfma_f32_16x16x32_bf16(ahi, Bh[ci][t2], acc[t2][0], 0, 0, 0);
                        acc[t2][1] = __builtin_amdgcn_mfma_f32_16x16x32_bf16(ahi, Bl[ci][t2], acc[t2][1], 0, 0, 0);
                        acc[t2][2] = __builtin_amdgcn_mfma_f32_16x16x32_bf16(alo, Bh[ci][t2], acc[t2][2], 0, 0, 0);
                    }
                }
                #pragma unroll
                for (int t2 = 0; t2 < 2; ++t2)
                    #pragma unroll
                    for (int r = 0; r < 4; ++r)
                        part[kq][np * 2 + t2][(l >> 4) * 4 + r][lan15] =
                            acc[t2][0][r] + acc[t2][1][r] + acc[t2][2][r];
            }
            __syncthreads();

            // cell phase (r7-verified math)
            if (tid < 256) {
                const int bb = tid >> 4, j2 = tid & 15;
                if (rval[bb]) {
                    const int b = brow[bb], t_ = trow[bb];
                    const int hh = hh0 + j2;
                    const float m0 = msk[bb][0], m1 = msk[bb][1], m2 = msk[bb][2];
                    float g[6];
                    #pragma unroll
                    for (int q = 0; q < 6; ++q) {
                        int gc = q * CH + hh;
                        g[q] = part[0][q][bb][j2] + part[1][q][bb][j2]
                             + part[2][q][bb][j2] + part[3][q][bb][j2]
                             + Wx_b[gc] + m0 * Uh_b[gc] + m1 * Uh_b[CG_ + gc]
                                        + m2 * Uh_b[2 * CG_ + gc];
                    }
                    float ig = 1.0f / (1.0f + expf(-g[0]));
                    float og = 1.0f / (1.0f + expf(-g[1]));
                    float ug = tanhf(g[2]);
                    float c = ig * ug;
                    if (m0 != 0.0f) c += (1.0f / (1.0f + expf(-g[3]))) *
                        __hip_atomic_load(&c_s[((size_t)cix[bb][0] * CB + b) * CH + hh],
                                          __ATOMIC_RELAXED, __HIP_MEMORY_SCOPE_AGENT);
                    if (m1 != 0.0f) c += (1.0f / (1.0f + expf(-g[4]))) *
                        __hip_atomic_load(&c_s[((size_t)cix[bb][1] * CB + b) * CH + hh],
                                          __ATOMIC_RELAXED, __HIP_MEMORY_SCOPE_AGENT);
                    if (m2 != 0.0f) c += (1.0f / (1.0f + expf(-g[5]))) *
                        __hip_atomic_load(&c_s[((size_t)cix[bb][2] * CB + b) * CH + hh],
                                          __ATOMIC_RELAXED, __HIP_MEMORY_SCOPE_AGENT);
                    float h = og * tanhf(c);
                    const size_t hx = ((size_t)t_ * CB + b) * CH + hh;
                    u16 hb = f2bfu(h);
                    u32 hp = ((u32)hb << 16) | (u32)f2bfu(h - bfu2f(hb));
                    __hip_atomic_store(&h_pk[hx], hp, __ATOMIC_RELAXED, __HIP_MEMORY_SCOPE_AGENT);
                    __hip_atomic_store(&c_s[hx], c, __ATOMIC_RELAXED, __HIP_MEMORY_SCOPE_AGENT);
                    if (t_ == CN - 1) out[(size_t)b * CH + hh] = h;
                }
            }
            __syncthreads();                   // protect LDS for next task
        }

        if (L == NL - 1) break;                // no barrier after last level

        // ---- light grid barrier per level (r12-verified mechanism) ----
        __syncthreads();
        if (tid == 0)
            __hip_atomic_store(&flags[bid * 16], L + 1,
                               __ATOMIC_RELAXED, __HIP_MEMORY_SCOPE_AGENT);
        for (;;) {
            int ok = 1;
            if (tid < 256)
                ok = (__hip_atomic_load(&flags[tid * 16], __ATOMIC_RELAXED,
                                        __HIP_MEMORY_SCOPE_AGENT) >= L + 1);
            if (__syncthreads_and(ok)) break;
            __builtin_amdgcn_s_sleep(2);
        }
    }
}

// ---------------------------------------------------------------------------
// Fallback: r10-verified per-step MFMA kernel (used only if ws too small).
// ---------------------------------------------------------------------------
__global__ __launch_bounds__(768) void tree_step_mfma(
    const int* __restrict__ node_ids, const int* __restrict__ children,
    const float* __restrict__ emb,
    const u16* __restrict__ Whi, const u16* __restrict__ Wlo,
    const float* __restrict__ Wx_b, const float* __restrict__ Uh_b,
    u16* __restrict__ h_hi, u16* __restrict__ h_lo,
    float* __restrict__ c_s, float* __restrict__ out, const int t)
{
    const int tid = threadIdx.x;
    const int xcd  = blockIdx.x & 7;
    const int bidx = blockIdx.x >> 3;
    const int hi   = xcd * 2 + (bidx & 1);
    const int bi   = bidx >> 1;
    const int b0   = bi * 16;
    const int hh0  = hi * 16;

    __shared__ u16   Ahi[16][ASTR];
    __shared__ u16   Alo[16][ASTR];
    __shared__ float part[4][6][16][17];
    __shared__ int   nid[16];
    __shared__ float msk[16][3];
    __shared__ int   cix[16][3];

    const int wv    = tid >> 6;
    const int l     = tid & 63;
    const int np    = wv % 3;
    const int kq    = wv / 3;
    const int lan15 = l & 15;
    const int k8    = (l >> 4) * 8;

    if (tid < 16) nid[tid] = node_ids[(size_t)(b0 + tid) * CN + t];
    if (tid < 48) {
        int lb = tid / 3, k = tid - lb * 3;
        int raw = children[((size_t)(b0 + lb) * CN + t) * CK + k];
        int v = raw < t;
        msk[lb][k] = v ? 1.0f : 0.0f;
        cix[lb][k] = v ? raw : 0;
    }
    __syncthreads();

    for (int idx = tid; idx < 1024; idx += 768) {
        int lb = idx >> 6, c4 = idx & 63;
        float4v v = *(const float4v*)(emb + (size_t)nid[lb] * CE + c4 * 4);
        ushort4v h4, l4;
        #pragma unroll
        for (int j = 0; j < 4; ++j) {
            u16 hb = f2bfu(v[j]);
            h4[j] = hb;
            l4[j] = f2bfu(v[j] - bfu2f(hb));
        }
        *(ushort4v*)&Ahi[lb][c4 * 4] = h4;
        *(ushort4v*)&Alo[lb][c4 * 4] = l4;
    }
    for (int idx = tid; idx < 3072; idx += 768) {
        int r  = idx >> 6;
        int c  = idx & 63;
        int pl = c >> 5;
        int ch = c & 31;
        int lb = r / 3, k = r - lb * 3;
        uint4v val = (uint4v){0u, 0u, 0u, 0u};
        if (msk[lb][k] != 0.0f) {
            const u16* src = (pl ? h_lo : h_hi)
                + ((size_t)cix[lb][k] * CB + (b0 + lb)) * CH + ch * 8;
            val = *(const uint4v*)src;
        }
        u16* dst = (pl ? &Alo[lb][CE + k * CH + ch * 8]
                       : &Ahi[lb][CE + k * CH + ch * 8]);
        *(uint4v*)dst = val;
    }
    __syncthreads();

    {
        float4v acc[2][3];
        #pragma unroll
        for (int a = 0; a < 2; ++a)
            #pragma unroll
            for (int b2 = 0; b2 < 3; ++b2)
                acc[a][b2] = (float4v){0.f, 0.f, 0.f, 0.f};
        size_t bbase0 = (size_t)((np * 2 + 0) * CH + hh0 + lan15) * KTOT + k8;
        size_t bbase1 = (size_t)((np * 2 + 1) * CH + hh0 + lan15) * KTOT + k8;
        #pragma unroll
        for (int ci = 0; ci < 8; ++ci) {
            const int kb = (kq * 8 + ci) * 32 + k8;
            const int kbg = (kq * 8 + ci) * 32;
            short8v ahi = *(const short8v*)&Ahi[lan15][kb];
            short8v alo = *(const short8v*)&Alo[lan15][kb];
            short8v bh0 = *(const short8v*)(Whi + bbase0 + kbg);
            short8v bh1 = *(const short8v*)(Whi + bbase1 + kbg);
            short8v bl0 = *(const short8v*)(Wlo + bbase0 + kbg);
            short8v bl1 = *(const short8v*)(Wlo + bbase1 + kbg);
            acc[0][0] = __builtin_amdgcn_mfma_f32_16x16x32_bf16(ahi, bh0, acc[0][0], 0, 0, 0);
            acc[0][1] = __builtin_amdgcn_mfma_f32_16x16x32_bf16(ahi, bl0, acc[0][1], 0, 0, 0);
            acc[0][2] = __builtin_amdgcn_mfma_f32_16x16x32_bf16(alo, bh0, acc[0][2], 0, 0, 0);
            acc[1][0] = __builtin_amdgcn_mfma_f32_16x16x32_bf16(ahi, bh1, acc[1][0], 0, 0, 0);
            acc[1][1] = __builtin_amdgcn_mfma_f32_16x16x32_bf16(ahi, bl1, acc[1][1], 0, 0, 0);
            acc[1][2] = __builtin_amdgcn_mfma_f32_16x16x32_bf16(alo, bh1, acc[1][2], 0, 0, 0);
        }
        #pragma unroll
        for (int t2 = 0; t2 < 2; ++t2)
            #pragma unroll
            for (int r = 0; r < 4; ++r)
                part[kq][np * 2 + t2][(l >> 4) * 4 + r][lan15] =
                    acc[t2][0][r] + acc[t2][1][r] + acc[t2][2][r];
    }
    __syncthreads();

    if (tid < 256) {
        const int bb = tid >> 4, j2 = tid & 15;
        const int b = b0 + bb, hh = hh0 + j2;
        const float m0 = msk[bb][0], m1 = msk[bb][1], m2 = msk[bb][2];
        float g[6];
        #pragma unroll
        for (int q = 0; q < 6; ++q) {
            int gc = q * CH + hh;
            g[q] = part[0][q][bb][j2] + part[1][q][bb][j2]
                 + part[2][q][bb][j2] + part[3][q][bb][j2]
                 + Wx_b[gc] + m0 * Uh_b[gc] + m1 * Uh_b[CG_ + gc]
                            + m2 * Uh_b[2 * CG_ + gc];
        }
        float ig = 1.0f / (1.0f + expf(-g[0]));
        float og = 1.0f / (1.0f + expf(-g[1]));
        float ug = tanhf(g[2]);
        float c = ig * ug;
        if (m0 != 0.0f) c += (1.0f / (1.0f + expf(-g[3]))) * c_s[((size_t)cix[bb][0] * CB + b) * CH + hh];
        if (m1 != 0.0f) c += (1.0f / (1.0f + expf(-g[4]))) * c_s[((size_t)cix[bb][1] * CB + b) * CH + hh];
        if (m2 != 0.0f) c += (1.0f / (1.0f + expf(-g[5]))) * c_s[((size_t)cix[bb][2] * CB + b) * CH + hh];
        float h = og * tanhf(c);
        const size_t hx = ((size_t)t * CB + b) * CH + hh;
        u16 hb = f2bfu(h);
        h_hi[hx] = hb;
        h_lo[hx] = f2bfu(h - bfu2f(hb));
        c_s[hx] = c;
        if (t == CN - 1) out[(size_t)b * CH + hh] = h;
    }
}

__global__ void ws_report(float* out, int n, float val) {
    int i = blockIdx.x * blockDim.x + threadIdx.x;
    if (i < n) out[i] = val;
}

// ---------------------------------------------------------------------------
extern "C" void kernel_launch(void* const* d_in, const int* in_sizes, int n_in,
                              void* d_out, int out_size, void* d_ws, size_t ws_size,
                              hipStream_t stream) {
    float* outp = (float*)d_out;

    const int expect_sizes[7] = {65536, 196608, 8192000, 393216, 1536, 1179648, 4608};
    int bad = -1;
    if (n_in != 7) bad = 7;
    else for (int i = 0; i < 7; ++i) if (in_sizes[i] != expect_sizes[i]) { bad = i; break; }
    if (bad >= 0) {
        ws_report<<<(out_size + 255) / 256, 256, 0, stream>>>(outp, out_size, 1000.0f + bad);
        return;
    }

    const int*   node_ids = (const int*)d_in[0];
    const int*   children = (const int*)d_in[1];
    const float* emb      = (const float*)d_in[2];
    const float* Wx_w     = (const float*)d_in[3];
    const float* Wx_b     = (const float*)d_in[4];
    const float* Uh_w     = (const float*)d_in[5];
    const float* Uh_b     = (const float*)d_in[6];

    const size_t w_plane  = (size_t)CG_ * KTOT * 2;       //  3,145,728 B
    const size_t st_elems = (size_t)CN * CB * CH;         // 16,777,216
    const size_t flags_sz = 256 * 16 * sizeof(u32);       // 16 KB
    const size_t wl_sz    = (size_t)CB * CN * sizeof(u16);// 128 KB
    const size_t lvl_sz   = 256 * sizeof(u32);            // 1 KB each

    // level-path carve: Whi|Wlo|h_pk|c_s|flags|wl|lvl_start|lvl_cnt|nlev
    size_t off = 0;
    const size_t o_whi = off; off += w_plane;
    const size_t o_wlo = off; off += w_plane;
    const size_t o_hpk = off; off += st_elems * 4;
    const size_t o_cs  = off; off += st_elems * 4;
    const size_t o_flg = off; off += flags_sz;
    const size_t o_wl  = off; off += wl_sz;
    const size_t o_ls  = off; off += lvl_sz;
    const size_t o_lc  = off; off += lvl_sz;
    const size_t o_nl  = off; off += 64;
    const size_t need_lvl  = off;                          // ~140.66 MB
    const size_t need_step = 2 * w_plane + st_elems * 2 * 2 + st_elems * 4; // 140.5 MB

    if (ws_size >= need_lvl) {
        char* w = (char*)d_ws;
        u16*   Whi = (u16*)(w + o_whi);
        u16*   Wlo = (u16*)(w + o_wlo);
        u32*   hpk = (u32*)(w + o_hpk);
        float* csb = (float*)(w + o_cs);
        u32*   flg = (u32*)(w + o_flg);
        u16*   wlp = (u16*)(w + o_wl);
        u32*   lsp = (u32*)(w + o_ls);
        u32*   lcp = (u32*)(w + o_lc);
        u32*   nlp = (u32*)(w + o_nl);

        prep_w<<<dim3(CG_), dim3(256), 0, stream>>>(Wx_w, Uh_w, Whi, Wlo);
        build_sched<<<dim3(1), dim3(256), 0, stream>>>(children, wlp, lsp, lcp, nlp);
        hipMemsetAsync(flg, 0, flags_sz, stream);

        void* args[] = { (void*)&node_ids, (void*)&children, (void*)&emb,
                         (void*)&Whi, (void*)&Wlo, (void*)&Wx_b, (void*)&Uh_b,
                         (void*)&hpk, (void*)&csb, (void*)&flg,
                         (void*)&wlp, (void*)&lsp, (void*)&lcp, (void*)&nlp,
                         (void*)&outp };
        hipError_t e = hipLaunchCooperativeKernel((const void*)tree_scan_lvl,
                                                  dim3(256), dim3(768), args, 0, stream);
        if (e == hipSuccess) return;
        // fall through on coop failure
    }
    if (ws_size >= need_step) {
        char* w = (char*)d_ws;
        u16*   Whi = (u16*)w;
        u16*   Wlo = (u16*)(w + w_plane);
        u16*   hhi = (u16*)(w + 2 * w_plane);
        u16*   hlo = (u16*)(w + 2 * w_plane + st_elems * 2);
        float* csb = (float*)(w + 2 * w_plane + 2 * st_elems * 2);

        prep_w<<<dim3(CG_), dim3(256), 0, stream>>>(Wx_w, Uh_w, Whi, Wlo);
        for (int t = 0; t < CN; ++t)
            tree_step_mfma<<<dim3(256), dim3(768), 0, stream>>>(
                node_ids, children, emb, Whi, Wlo, Wx_b, Uh_b,
                hhi, hlo, csb, outp, t);
    } else {
        ws_report<<<(out_size + 255) / 256, 256, 0, stream>>>(
            outp, out_size, (float)(ws_size >> 20));
    }
}

// Round 15
// 3912.655 us; speedup vs baseline: 1.2242x; 1.1009x over previous
//
#include <hip/hip_runtime.h>
#include <hip/hip_bf16.h>

#define CB 256      // batch
#define CN 256      // nodes
#define CK 3        // children per node
#define CE 256      // embedding dim
#define CH 256      // hidden dim
#define CG_ 1536    // gates = 6*CH
#define KTOT 1024   // E + K*H
#define APAD 8
#define ASTR (KTOT + APAD)   // LDS A row stride (shorts) = 1032 (2064 B)

typedef __attribute__((ext_vector_type(8))) short short8v;          // 8 bf16
typedef __attribute__((ext_vector_type(4))) float float4v;          // MFMA C/D
typedef __attribute__((ext_vector_type(4))) unsigned int uint4v;
typedef __attribute__((ext_vector_type(4))) unsigned short ushort4v;
typedef unsigned int u32;
typedef unsigned long long u64;
typedef unsigned short u16;

__device__ __forceinline__ u16 f2bfu(float v) {
    __hip_bfloat16 h = __float2bfloat16(v);
    return __builtin_bit_cast(u16, h);
}
__device__ __forceinline__ float bfu2f(u16 u) {
    __hip_bfloat16 h = __builtin_bit_cast(__hip_bfloat16, u);
    return __bfloat162float(h);
}

// ---------------------------------------------------------------------------
// Prep (verified r8-r14): split virtual W = [Wx_w ; Uh_w] (1024 x 1536) into
// K-major bf16 hi/lo planes [g][k].
// ---------------------------------------------------------------------------
__global__ __launch_bounds__(256) void prep_w(
    const float* __restrict__ Wx_w, const float* __restrict__ Uh_w,
    u16* __restrict__ Whi, u16* __restrict__ Wlo)
{
    const int g = blockIdx.x;
    for (int k = threadIdx.x; k < KTOT; k += 256) {
        float w = (k < CE) ? Wx_w[(size_t)k * CG_ + g]
                           : Uh_w[(size_t)(k - CE) * CG_ + g];
        u16 hi = f2bfu(w);
        Whi[(size_t)g * KTOT + k] = hi;
        Wlo[(size_t)g * KTOT + k] = f2bfu(w - bfu2f(hi));
    }
}

// ---------------------------------------------------------------------------
// Level schedule build (verified r14, incl. the 0xFFFF-collision fix).
// ---------------------------------------------------------------------------
__global__ __launch_bounds__(256) void build_sched(
    const int* __restrict__ children,
    u16* __restrict__ wl,             // [65536] (b<<8)|t
    u32* __restrict__ lvl_start,      // [256]
    u32* __restrict__ lvl_cnt,        // [256]
    u32* __restrict__ nlev)           // [1]
{
    __shared__ unsigned char lvl[CB][CN];   // 64 KB
    __shared__ u32 cnt[CN];
    __shared__ u32 pos[CN];
    const int b = threadIdx.x;

    for (int t = 0; t < CN; ++t) {
        int lv = 0;
        #pragma unroll
        for (int k = 0; k < CK; ++k) {
            int raw = children[((size_t)b * CN + t) * CK + k];
            if (raw < t) { int cl = (int)lvl[b][raw] + 1; if (cl > lv) lv = cl; }
        }
        lvl[b][t] = (unsigned char)lv;
    }
    cnt[b] = 0;
    __syncthreads();
    for (int t = 0; t < CN; ++t) atomicAdd(&cnt[lvl[b][t]], 1u);
    __syncthreads();
    if (b == 0) {
        u32 acc = 0, nl = 0;
        for (int L = 0; L < CN; ++L) {
            pos[L] = acc;
            if (cnt[L]) nl = (u32)L + 1;
            acc += cnt[L];
        }
        *nlev = nl;
    }
    __syncthreads();
    lvl_cnt[b]   = cnt[b];
    lvl_start[b] = pos[b];
    __syncthreads();
    for (int t = 0; t < CN; ++t) {
        int L = lvl[b][t];
        u32 p = atomicAdd(&pos[L], 1u);
        wl[p] = (u16)((b << 8) | t);
    }
}

// ---------------------------------------------------------------------------
// LEVEL-SCHEDULED persistent scan, S=4 hh-slices (r15).
// r14 counters: 4.0 GB beyond-L2 traffic @ 950 GB/s = the whole runtime;
// root cause = child-h gather replicated x16 across hh-slices. S=16 -> S=4
// cuts gather traffic 4x. Each block: 64 H-cols (384 gate cols) x 16 rows.
// 12 waves x 2 col-tiles x full-K(1024) MFMA chains (no kq split -> part
// halved, no cross-wave K reduction). Cell: 512 thr x 2 cols. All schedule/
// sync/atomic machinery identical to r14 (verified).
// hi=(bid&7)>>1: slice pinned to 2 XCDs -> W slice (1.5 MB) L2-resident.
// ---------------------------------------------------------------------------
__global__ __launch_bounds__(768, 3) void tree_scan_lvl(
    const int* __restrict__ node_ids,          // [B][N]
    const int* __restrict__ children,          // [B][N][K]
    const float* __restrict__ emb,             // [V][E]
    const u16* __restrict__ Whi,               // [1536][1024]
    const u16* __restrict__ Wlo,               // [1536][1024]
    const float* __restrict__ Wx_b,            // [G]
    const float* __restrict__ Uh_b,            // [K][G]
    u32* __restrict__ h_pk,                    // [N][B][H] u32 (hi16|lo16)
    float* __restrict__ c_s,                   // [N][B][H] f32
    u32* __restrict__ flags,                   // [256*16], zeroed per call
    const u16* __restrict__ wl,                // [65536]
    const u32* __restrict__ lvl_start,         // [256]
    const u32* __restrict__ lvl_cnt,           // [256]
    const u32* __restrict__ nlev_p,            // [1]
    float* __restrict__ out)                   // [B][H] f32
{
    const int tid = threadIdx.x;
    const int bid = blockIdx.x;
    const int hi  = (bid & 7) >> 1;                     // 0..3 (2 XCDs/slice)
    const int sub = ((bid >> 3) << 1) | (bid & 1);      // 0..63
    const int hh0 = hi * 64;

    __shared__ u16   Ahi[16][ASTR];            // 33,024 B
    __shared__ u16   Alo[16][ASTR];            // 33,024 B
    __shared__ float part[24][16][17];         // 26,112 B  [col-tile][bb][lane]
    __shared__ int   nid[16], brow[16], trow[16];
    __shared__ unsigned char rval[16];
    __shared__ float msk[16][3];
    __shared__ int   cix[16][3];

    const int wv    = tid >> 6;                // 0..11
    const int l     = tid & 63;
    const int lan15 = l & 15;
    const int k8    = (l >> 4) * 8;

    // this wave's two col-tiles: ct = 2wv+t2; gate col = (ct>>2)*256 + hh0 +
    // (ct&3)*16 + lan15
    size_t bbase[2];
    #pragma unroll
    for (int t2 = 0; t2 < 2; ++t2) {
        int ct = 2 * wv + t2;
        bbase[t2] = (size_t)((ct >> 2) * CH + hh0 + (ct & 3) * 16 + lan15) * KTOT + k8;
    }

    const u32 NL = *nlev_p;

    for (u32 L = 0; L < NL; ++L) {
        const u32 lcnt   = lvl_cnt[L];
        const u32 lst    = lvl_start[L];
        const u32 nchunk = (lcnt + 15) >> 4;

        for (u32 ck = sub; ck < nchunk; ck += 64) {
            if (tid < 16) {
                u32 i = ck * 16 + (u32)tid;
                int valid = (i < lcnt);
                u16 e = valid ? wl[lst + i] : (u16)0;
                rval[tid] = (unsigned char)valid;
                int b_ = valid ? (e >> 8) : 0;
                int t_ = valid ? (e & 0xFF) : 0;
                brow[tid] = b_;
                trow[tid] = t_;
                nid[tid]  = node_ids[(size_t)b_ * CN + t_];
            }
            if (tid < 48) {
                int lb = tid / 3, k = tid - lb * 3;
                int b_ = brow[lb], t_ = trow[lb];
                int raw = children[((size_t)b_ * CN + t_) * CK + k];
                int v = (raw < t_) && rval[lb];
                msk[lb][k] = v ? 1.0f : 0.0f;
                cix[lb][k] = v ? raw : 0;
            }
            __syncthreads();

            // stage x: 16 rows x 64 float4 chunks; split hi/lo in-register
            for (int idx = tid; idx < 1024; idx += 768) {
                int lb = idx >> 6, c4 = idx & 63;
                float4v v = *(const float4v*)(emb + (size_t)nid[lb] * CE + c4 * 4);
                ushort4v h4, l4;
                #pragma unroll
                for (int j = 0; j < 4; ++j) {
                    u16 hb = f2bfu(v[j]);
                    h4[j] = hb;
                    l4[j] = f2bfu(v[j] - bfu2f(hb));
                }
                *(ushort4v*)&Ahi[lb][c4 * 4] = h4;
                *(ushort4v*)&Alo[lb][c4 * 4] = l4;
            }
            // stage h: 48 (lb,k) rows x 128 u64 chunks of packed u32 pairs
            for (int idx = tid; idx < 6144; idx += 768) {
                int r  = idx >> 7;             // 0..47
                int ch = idx & 127;
                int lb = r / 3, k = r - lb * 3;
                u64 v = 0;
                if (msk[lb][k] != 0.0f) {
                    const u64* src = (const u64*)(h_pk
                        + ((size_t)cix[lb][k] * CB + brow[lb]) * CH + 2 * ch);
                    v = __hip_atomic_load(src, __ATOMIC_RELAXED, __HIP_MEMORY_SCOPE_AGENT);
                }
                u32 e0 = (u32)v, e1 = (u32)(v >> 32);
                int cc = CE + k * CH + 2 * ch;
                *(u32*)&Ahi[lb][cc] = (e0 >> 16) | (e1 & 0xffff0000u);
                *(u32*)&Alo[lb][cc] = (e0 & 0xffffu) | (e1 << 16);
            }
            __syncthreads();

            // MFMA bf16x3: full-K chains, 2 col-tiles per wave
            {
                float4v acc[2][3];
                #pragma unroll
                for (int a = 0; a < 2; ++a)
                    #pragma unroll
                    for (int b2 = 0; b2 < 3; ++b2)
                        acc[a][b2] = (float4v){0.f, 0.f, 0.f, 0.f};

                #pragma unroll 8
                for (int ci = 0; ci < 32; ++ci) {
                    const int kb = ci * 32 + k8;
                    short8v ahi = *(const short8v*)&Ahi[lan15][kb];
                    short8v alo = *(const short8v*)&Alo[lan15][kb];
                    #pragma unroll
                    for (int t2 = 0; t2 < 2; ++t2) {
                        short8v bh = *(const short8v*)(Whi + bbase[t2] + ci * 32);
                        short8v bl = *(const short8v*)(Wlo + bbase[t2] + ci * 32);
                        acc[t2][0] = __builtin_amdgcn_mfma_f32_16x16x32_bf16(ahi, bh, acc[t2][0], 0, 0, 0);
                        acc[t2][1] = __builtin_amdgcn_mfma_f32_16x16x32_bf16(ahi, bl, acc[t2][1], 0, 0, 0);
                        acc[t2][2] = __builtin_amdgcn_mfma_f32_16x16x32_bf16(alo, bh, acc[t2][2], 0, 0, 0);
                    }
                }
                #pragma unroll
                for (int t2 = 0; t2 < 2; ++t2)
                    #pragma unroll
                    for (int r = 0; r < 4; ++r)
                        part[2 * wv + t2][(l >> 4) * 4 + r][lan15] =
                            acc[t2][0][r] + acc[t2][1][r] + acc[t2][2][r];
            }
            __syncthreads();

            // cell phase (r7-verified math): 512 threads x 2 H-cols
            if (tid < 512) {
                const int bb = (tid >> 5) & 15;
                const int j  = tid & 31;
                if (rval[bb]) {
                    const int b = brow[bb], t_ = trow[bb];
                    const float m0 = msk[bb][0], m1 = msk[bb][1], m2 = msk[bb][2];
                    #pragma unroll
                    for (int c2 = 0; c2 < 2; ++c2) {
                        const int jl = j + 32 * c2;        // 0..63
                        const int hh = hh0 + jl;
                        const int ctq = jl >> 4;           // 16-col tile in gate
                        const int lane = jl & 15;
                        float g[6];
                        #pragma unroll
                        for (int q = 0; q < 6; ++q) {
                            int gc = q * CH + hh;
                            g[q] = part[q * 4 + ctq][bb][lane]
                                 + Wx_b[gc] + m0 * Uh_b[gc] + m1 * Uh_b[CG_ + gc]
                                            + m2 * Uh_b[2 * CG_ + gc];
                        }
                        float ig = 1.0f / (1.0f + expf(-g[0]));
                        float og = 1.0f / (1.0f + expf(-g[1]));
                        float ug = tanhf(g[2]);
                        float c = ig * ug;
                        if (m0 != 0.0f) c += (1.0f / (1.0f + expf(-g[3]))) *
                            __hip_atomic_load(&c_s[((size_t)cix[bb][0] * CB + b) * CH + hh],
                                              __ATOMIC_RELAXED, __HIP_MEMORY_SCOPE_AGENT);
                        if (m1 != 0.0f) c += (1.0f / (1.0f + expf(-g[4]))) *
                            __hip_atomic_load(&c_s[((size_t)cix[bb][1] * CB + b) * CH + hh],
                                              __ATOMIC_RELAXED, __HIP_MEMORY_SCOPE_AGENT);
                        if (m2 != 0.0f) c += (1.0f / (1.0f + expf(-g[5]))) *
                            __hip_atomic_load(&c_s[((size_t)cix[bb][2] * CB + b) * CH + hh],
                                              __ATOMIC_RELAXED, __HIP_MEMORY_SCOPE_AGENT);
                        float h = og * tanhf(c);
                        const size_t hx = ((size_t)t_ * CB + b) * CH + hh;
                        u16 hb = f2bfu(h);
                        u32 hp = ((u32)hb << 16) | (u32)f2bfu(h - bfu2f(hb));
                        __hip_atomic_store(&h_pk[hx], hp, __ATOMIC_RELAXED, __HIP_MEMORY_SCOPE_AGENT);
                        __hip_atomic_store(&c_s[hx], c, __ATOMIC_RELAXED, __HIP_MEMORY_SCOPE_AGENT);
                        if (t_ == CN - 1) out[(size_t)b * CH + hh] = h;
                    }
                }
            }
            __syncthreads();                   // protect LDS for next task
        }

        if (L == NL - 1) break;

        // ---- light grid barrier per level (r12/r14-verified mechanism) ----
        __syncthreads();
        if (tid == 0)
            __hip_atomic_store(&flags[bid * 16], L + 1,
                               __ATOMIC_RELAXED, __HIP_MEMORY_SCOPE_AGENT);
        for (;;) {
            int ok = 1;
            if (tid < 256)
                ok = (__hip_atomic_load(&flags[tid * 16], __ATOMIC_RELAXED,
                                        __HIP_MEMORY_SCOPE_AGENT) >= L + 1);
            if (__syncthreads_and(ok)) break;
            __builtin_amdgcn_s_sleep(2);
        }
    }
}

// ---------------------------------------------------------------------------
// Fallback: r10-verified per-step MFMA kernel (used only if ws too small).
// ---------------------------------------------------------------------------
__global__ __launch_bounds__(768) void tree_step_mfma(
    const int* __restrict__ node_ids, const int* __restrict__ children,
    const float* __restrict__ emb,
    const u16* __restrict__ Whi, const u16* __restrict__ Wlo,
    const float* __restrict__ Wx_b, const float* __restrict__ Uh_b,
    u16* __restrict__ h_hi, u16* __restrict__ h_lo,
    float* __restrict__ c_s, float* __restrict__ out, const int t)
{
    const int tid = threadIdx.x;
    const int xcd  = blockIdx.x & 7;
    const int bidx = blockIdx.x >> 3;
    const int hi   = xcd * 2 + (bidx & 1);
    const int bi   = bidx >> 1;
    const int b0   = bi * 16;
    const int hh0  = hi * 16;

    __shared__ u16   Ahi[16][ASTR];
    __shared__ u16   Alo[16][ASTR];
    __shared__ float part[4][6][16][17];
    __shared__ int   nid[16];
    __shared__ float msk[16][3];
    __shared__ int   cix[16][3];

    const int wv    = tid >> 6;
    const int l     = tid & 63;
    const int np    = wv % 3;
    const int kq    = wv / 3;
    const int lan15 = l & 15;
    const int k8    = (l >> 4) * 8;

    if (tid < 16) nid[tid] = node_ids[(size_t)(b0 + tid) * CN + t];
    if (tid < 48) {
        int lb = tid / 3, k = tid - lb * 3;
        int raw = children[((size_t)(b0 + lb) * CN + t) * CK + k];
        int v = raw < t;
        msk[lb][k] = v ? 1.0f : 0.0f;
        cix[lb][k] = v ? raw : 0;
    }
    __syncthreads();

    for (int idx = tid; idx < 1024; idx += 768) {
        int lb = idx >> 6, c4 = idx & 63;
        float4v v = *(const float4v*)(emb + (size_t)nid[lb] * CE + c4 * 4);
        ushort4v h4, l4;
        #pragma unroll
        for (int j = 0; j < 4; ++j) {
            u16 hb = f2bfu(v[j]);
            h4[j] = hb;
            l4[j] = f2bfu(v[j] - bfu2f(hb));
        }
        *(ushort4v*)&Ahi[lb][c4 * 4] = h4;
        *(ushort4v*)&Alo[lb][c4 * 4] = l4;
    }
    for (int idx = tid; idx < 3072; idx += 768) {
        int r  = idx >> 6;
        int c  = idx & 63;
        int pl = c >> 5;
        int ch = c & 31;
        int lb = r / 3, k = r - lb * 3;
        uint4v val = (uint4v){0u, 0u, 0u, 0u};
        if (msk[lb][k] != 0.0f) {
            const u16* src = (pl ? h_lo : h_hi)
                + ((size_t)cix[lb][k] * CB + (b0 + lb)) * CH + ch * 8;
            val = *(const uint4v*)src;
        }
        u16* dst = (pl ? &Alo[lb][CE + k * CH + ch * 8]
                       : &Ahi[lb][CE + k * CH + ch * 8]);
        *(uint4v*)dst = val;
    }
    __syncthreads();

    {
        float4v acc[2][3];
        #pragma unroll
        for (int a = 0; a < 2; ++a)
            #pragma unroll
            for (int b2 = 0; b2 < 3; ++b2)
                acc[a][b2] = (float4v){0.f, 0.f, 0.f, 0.f};
        size_t bbase0 = (size_t)((np * 2 + 0) * CH + hh0 + lan15) * KTOT + k8;
        size_t bbase1 = (size_t)((np * 2 + 1) * CH + hh0 + lan15) * KTOT + k8;
        #pragma unroll
        for (int ci = 0; ci < 8; ++ci) {
            const int kb = (kq * 8 + ci) * 32 + k8;
            const int kbg = (kq * 8 + ci) * 32;
            short8v ahi = *(const short8v*)&Ahi[lan15][kb];
            short8v alo = *(const short8v*)&Alo[lan15][kb];
            short8v bh0 = *(const short8v*)(Whi + bbase0 + kbg);
            short8v bh1 = *(const short8v*)(Whi + bbase1 + kbg);
            short8v bl0 = *(const short8v*)(Wlo + bbase0 + kbg);
            short8v bl1 = *(const short8v*)(Wlo + bbase1 + kbg);
            acc[0][0] = __builtin_amdgcn_mfma_f32_16x16x32_bf16(ahi, bh0, acc[0][0], 0, 0, 0);
            acc[0][1] = __builtin_amdgcn_mfma_f32_16x16x32_bf16(ahi, bl0, acc[0][1], 0, 0, 0);
            acc[0][2] = __builtin_amdgcn_mfma_f32_16x16x32_bf16(alo, bh0, acc[0][2], 0, 0, 0);
            acc[1][0] = __builtin_amdgcn_mfma_f32_16x16x32_bf16(ahi, bh1, acc[1][0], 0, 0, 0);
            acc[1][1] = __builtin_amdgcn_mfma_f32_16x16x32_bf16(ahi, bl1, acc[1][1], 0, 0, 0);
            acc[1][2] = __builtin_amdgcn_mfma_f32_16x16x32_bf16(alo, bh1, acc[1][2], 0, 0, 0);
        }
        #pragma unroll
        for (int t2 = 0; t2 < 2; ++t2)
            #pragma unroll
            for (int r = 0; r < 4; ++r)
                part[kq][np * 2 + t2][(l >> 4) * 4 + r][lan15] =
                    acc[t2][0][r] + acc[t2][1][r] + acc[t2][2][r];
    }
    __syncthreads();

    if (tid < 256) {
        const int bb = tid >> 4, j2 = tid & 15;
        const int b = b0 + bb, hh = hh0 + j2;
        const float m0 = msk[bb][0], m1 = msk[bb][1], m2 = msk[bb][2];
        float g[6];
        #pragma unroll
        for (int q = 0; q < 6; ++q) {
            int gc = q * CH + hh;
            g[q] = part[0][q][bb][j2] + part[1][q][bb][j2]
                 + part[2][q][bb][j2] + part[3][q][bb][j2]
                 + Wx_b[gc] + m0 * Uh_b[gc] + m1 * Uh_b[CG_ + gc]
                            + m2 * Uh_b[2 * CG_ + gc];
        }
        float ig = 1.0f / (1.0f + expf(-g[0]));
        float og = 1.0f / (1.0f + expf(-g[1]));
        float ug = tanhf(g[2]);
        float c = ig * ug;
        if (m0 != 0.0f) c += (1.0f / (1.0f + expf(-g[3]))) * c_s[((size_t)cix[bb][0] * CB + b) * CH + hh];
        if (m1 != 0.0f) c += (1.0f / (1.0f + expf(-g[4]))) * c_s[((size_t)cix[bb][1] * CB + b) * CH + hh];
        if (m2 != 0.0f) c += (1.0f / (1.0f + expf(-g[5]))) * c_s[((size_t)cix[bb][2] * CB + b) * CH + hh];
        float h = og * tanhf(c);
        const size_t hx = ((size_t)t * CB + b) * CH + hh;
        u16 hb = f2bfu(h);
        h_hi[hx] = hb;
        h_lo[hx] = f2bfu(h - bfu2f(hb));
        c_s[hx] = c;
        if (t == CN - 1) out[(size_t)b * CH + hh] = h;
    }
}

__global__ void ws_report(float* out, int n, float val) {
    int i = blockIdx.x * blockDim.x + threadIdx.x;
    if (i < n) out[i] = val;
}

// ---------------------------------------------------------------------------
extern "C" void kernel_launch(void* const* d_in, const int* in_sizes, int n_in,
                              void* d_out, int out_size, void* d_ws, size_t ws_size,
                              hipStream_t stream) {
    float* outp = (float*)d_out;

    const int expect_sizes[7] = {65536, 196608, 8192000, 393216, 1536, 1179648, 4608};
    int bad = -1;
    if (n_in != 7) bad = 7;
    else for (int i = 0; i < 7; ++i) if (in_sizes[i] != expect_sizes[i]) { bad = i; break; }
    if (bad >= 0) {
        ws_report<<<(out_size + 255) / 256, 256, 0, stream>>>(outp, out_size, 1000.0f + bad);
        return;
    }

    const int*   node_ids = (const int*)d_in[0];
    const int*   children = (const int*)d_in[1];
    const float* emb      = (const float*)d_in[2];
    const float* Wx_w     = (const float*)d_in[3];
    const float* Wx_b     = (const float*)d_in[4];
    const float* Uh_w     = (const float*)d_in[5];
    const float* Uh_b     = (const float*)d_in[6];

    const size_t w_plane  = (size_t)CG_ * KTOT * 2;       //  3,145,728 B
    const size_t st_elems = (size_t)CN * CB * CH;         // 16,777,216
    const size_t flags_sz = 256 * 16 * sizeof(u32);       // 16 KB
    const size_t wl_sz    = (size_t)CB * CN * sizeof(u16);// 128 KB
    const size_t lvl_sz   = 256 * sizeof(u32);

    size_t off = 0;
    const size_t o_whi = off; off += w_plane;
    const size_t o_wlo = off; off += w_plane;
    const size_t o_hpk = off; off += st_elems * 4;
    const size_t o_cs  = off; off += st_elems * 4;
    const size_t o_flg = off; off += flags_sz;
    const size_t o_wl  = off; off += wl_sz;
    const size_t o_ls  = off; off += lvl_sz;
    const size_t o_lc  = off; off += lvl_sz;
    const size_t o_nl  = off; off += 64;
    const size_t need_lvl  = off;
    const size_t need_step = 2 * w_plane + st_elems * 2 * 2 + st_elems * 4;

    if (ws_size >= need_lvl) {
        char* w = (char*)d_ws;
        u16*   Whi = (u16*)(w + o_whi);
        u16*   Wlo = (u16*)(w + o_wlo);
        u32*   hpk = (u32*)(w + o_hpk);
        float* csb = (float*)(w + o_cs);
        u32*   flg = (u32*)(w + o_flg);
        u16*   wlp = (u16*)(w + o_wl);
        u32*   lsp = (u32*)(w + o_ls);
        u32*   lcp = (u32*)(w + o_lc);
        u32*   nlp = (u32*)(w + o_nl);

        prep_w<<<dim3(CG_), dim3(256), 0, stream>>>(Wx_w, Uh_w, Whi, Wlo);
        build_sched<<<dim3(1), dim3(256), 0, stream>>>(children, wlp, lsp, lcp, nlp);
        hipMemsetAsync(flg, 0, flags_sz, stream);

        void* args[] = { (void*)&node_ids, (void*)&children, (void*)&emb,
                         (void*)&Whi, (void*)&Wlo, (void*)&Wx_b, (void*)&Uh_b,
                         (void*)&hpk, (void*)&csb, (void*)&flg,
                         (void*)&wlp, (void*)&lsp, (void*)&lcp, (void*)&nlp,
                         (void*)&outp };
        hipError_t e = hipLaunchCooperativeKernel((const void*)tree_scan_lvl,
                                                  dim3(256), dim3(768), args, 0, stream);
        if (e == hipSuccess) return;
    }
    if (ws_size >= need_step) {
        char* w = (char*)d_ws;
        u16*   Whi = (u16*)w;
        u16*   Wlo = (u16*)(w + w_plane);
        u16*   hhi = (u16*)(w + 2 * w_plane);
        u16*   hlo = (u16*)(w + 2 * w_plane + st_elems * 2);
        float* csb = (float*)(w + 2 * w_plane + 2 * st_elems * 2);

        prep_w<<<dim3(CG_), dim3(256), 0, stream>>>(Wx_w, Uh_w, Whi, Wlo);
        for (int t = 0; t < CN; ++t)
            tree_step_mfma<<<dim3(256), dim3(768), 0, stream>>>(
                node_ids, children, emb, Whi, Wlo, Wx_b, Uh_b,
                hhi, hlo, csb, outp, t);
    } else {
        ws_report<<<(out_size + 255) / 256, 256, 0, stream>>>(
            outp, out_size, (float)(ws_size >> 20));
    }
}